// Round 1
// baseline (822.212 us; speedup 1.0000x reference)
//
#include <hip/hip_runtime.h>
#include <math.h>

// BoundaryTransformerLayer: n=65536 pts, ns=16 neighbors, C=64, CW=8.
// Pipeline (stream-ordered, deterministic two-stage reductions):
//  K1 proj: xq/xk/xv = x@W.T+b            (stored in ws, 50 MB)
//  K2 stats of t1 = g_p@Wp1.T+bp1 (3ch)   -> bn_p scale/shift
//  K3 stats of w_pre = g_k - x_q + p_r    -> bn_w0 scale/shift (64ch)
//  K4 u = relu(bn_w0(w_pre))@Ww1.T+bw1 (stored, 33.5MB) + stats -> bn_w1
//  K5 softmax(relu(bn_w1(u))@Ww2.T+bw2) over ns; out = sum_j (g_v+p_r)*w

#define NB_STAT 1024

__device__ __forceinline__ float relu_(float v) { return v > 0.f ? v : 0.f; }

// ---------------- K1: q/k/v projections ----------------
__global__ __launch_bounds__(256) void k_proj(
    const float* __restrict__ x,
    const float* __restrict__ Wq, const float* __restrict__ bq,
    const float* __restrict__ Wk, const float* __restrict__ bk,
    const float* __restrict__ Wv, const float* __restrict__ bv,
    float* __restrict__ xq, float* __restrict__ xk, float* __restrict__ xv)
{
    __shared__ float wq_s[4096], wk_s[4096], wv_s[4096];   // W^T: [k][c]
    __shared__ float xs[16 * 64];
    __shared__ float bqs[64], bks[64], bvs[64];
    int tid = threadIdx.x;
    for (int i = tid; i < 4096; i += 256) {
        int r = i >> 6, k = i & 63;
        wq_s[k * 64 + r] = Wq[i];
        wk_s[k * 64 + r] = Wk[i];
        wv_s[k * 64 + r] = Wv[i];
    }
    if (tid < 64) { bqs[tid] = bq[tid]; bks[tid] = bk[tid]; bvs[tid] = bv[tid]; }
    size_t base = (size_t)blockIdx.x * 16;
    ((float4*)xs)[tid] = ((const float4*)(x + base * 64))[tid];
    __syncthreads();
    int c = tid & 63, w = tid >> 6;
    float aq[4], ak[4], av[4];
    #pragma unroll
    for (int pp = 0; pp < 4; ++pp) { aq[pp] = bqs[c]; ak[pp] = bks[c]; av[pp] = bvs[c]; }
    const float* xr = &xs[(w * 4) * 64];
    #pragma unroll 4
    for (int k = 0; k < 64; ++k) {
        float wqv = wq_s[k * 64 + c], wkv = wk_s[k * 64 + c], wvv = wv_s[k * 64 + c];
        #pragma unroll
        for (int pp = 0; pp < 4; ++pp) {
            float xv_ = xr[pp * 64 + k];
            aq[pp] = fmaf(xv_, wqv, aq[pp]);
            ak[pp] = fmaf(xv_, wkv, ak[pp]);
            av[pp] = fmaf(xv_, wvv, av[pp]);
        }
    }
    #pragma unroll
    for (int pp = 0; pp < 4; ++pp) {
        size_t pt = base + w * 4 + pp;
        xq[pt * 64 + c] = aq[pp];
        xk[pt * 64 + c] = ak[pp];
        xv[pt * 64 + c] = av[pp];
    }
}

// ---------------- K2: stats of t1 (3 channels) ----------------
__global__ __launch_bounds__(256) void k_stats_p(
    const float* __restrict__ p, const int* __restrict__ idx,
    const float* __restrict__ Wp1, const float* __restrict__ bp1,
    float* __restrict__ part, int M)
{
    int tid = threadIdx.x;
    float w[9], b[3];
    #pragma unroll
    for (int a = 0; a < 9; ++a) w[a] = Wp1[a];
    #pragma unroll
    for (int a = 0; a < 3; ++a) b[a] = bp1[a];
    float s0 = 0, s1 = 0, s2 = 0, q0 = 0, q1 = 0, q2 = 0;
    int step = gridDim.x * 256;
    for (int s = blockIdx.x * 256 + tid; s < M; s += step) {
        int i0 = s >> 4;
        int nb = idx[s];
        float g0 = p[nb * 3 + 0] - p[i0 * 3 + 0];
        float g1 = p[nb * 3 + 1] - p[i0 * 3 + 1];
        float g2 = p[nb * 3 + 2] - p[i0 * 3 + 2];
        float t0 = b[0] + w[0] * g0 + w[1] * g1 + w[2] * g2;
        float t1 = b[1] + w[3] * g0 + w[4] * g1 + w[5] * g2;
        float t2 = b[2] + w[6] * g0 + w[7] * g1 + w[8] * g2;
        s0 += t0; s1 += t1; s2 += t2;
        q0 = fmaf(t0, t0, q0); q1 = fmaf(t1, t1, q1); q2 = fmaf(t2, t2, q2);
    }
    __shared__ float red[4][6];
    float v[6] = { s0, s1, s2, q0, q1, q2 };
    #pragma unroll
    for (int k = 0; k < 6; ++k) {
        float a = v[k];
        for (int off = 32; off; off >>= 1) a += __shfl_down(a, off, 64);
        if ((tid & 63) == 0) red[tid >> 6][k] = a;
    }
    __syncthreads();
    if (tid < 6)
        part[(size_t)blockIdx.x * 6 + tid] = red[0][tid] + red[1][tid] + red[2][tid] + red[3][tid];
}

__global__ void k_fin_p(const float* __restrict__ part, int nbk, float invM,
                        const float* __restrict__ g, const float* __restrict__ b,
                        float* __restrict__ bnp)
{
    int t = threadIdx.x;
    __shared__ float tot[6];
    if (t < 6) {
        float a0 = 0, a1 = 0, a2 = 0, a3 = 0;
        for (int k = 0; k < nbk; k += 4) {
            a0 += part[(size_t)(k + 0) * 6 + t];
            a1 += part[(size_t)(k + 1) * 6 + t];
            a2 += part[(size_t)(k + 2) * 6 + t];
            a3 += part[(size_t)(k + 3) * 6 + t];
        }
        tot[t] = (a0 + a1) + (a2 + a3);
    }
    __syncthreads();
    if (t < 3) {
        float mean = tot[t] * invM;
        float var = tot[3 + t] * invM - mean * mean;
        float sc = g[t] * rsqrtf(var + 1e-5f);
        bnp[t] = sc;
        bnp[3 + t] = b[t] - mean * sc;
    }
}

// ---------------- K3: stats of w_pre (64 channels) ----------------
__global__ __launch_bounds__(256) void k_stats_w0(
    const float* __restrict__ p, const int* __restrict__ idx,
    const float* __restrict__ xq, const float* __restrict__ xk,
    const float* __restrict__ Wp1, const float* __restrict__ bp1,
    const float* __restrict__ bnp,
    const float* __restrict__ Wp2, const float* __restrict__ bp2,
    float* __restrict__ part, int M)
{
    int tid = threadIdx.x;
    int c = tid & 63, w = tid >> 6;
    float w1r[9], b1r[3];
    #pragma unroll
    for (int a = 0; a < 9; ++a) w1r[a] = Wp1[a];
    #pragma unroll
    for (int a = 0; a < 3; ++a) b1r[a] = bp1[a];
    float sp0 = bnp[0], sp1 = bnp[1], sp2 = bnp[2];
    float hp0 = bnp[3], hp1 = bnp[4], hp2 = bnp[5];
    float wa = Wp2[c * 3 + 0], wb = Wp2[c * 3 + 1], wcc = Wp2[c * 3 + 2], bc = bp2[c];
    float sum = 0.f, sq = 0.f;
    int step = gridDim.x * 4;
    for (int s = blockIdx.x * 4 + w; s < M; s += step) {
        int i0 = s >> 4;
        int nb = idx[s];
        float g0 = p[nb * 3 + 0] - p[i0 * 3 + 0];
        float g1 = p[nb * 3 + 1] - p[i0 * 3 + 1];
        float g2 = p[nb * 3 + 2] - p[i0 * 3 + 2];
        float e0 = relu_((b1r[0] + w1r[0] * g0 + w1r[1] * g1 + w1r[2] * g2) * sp0 + hp0);
        float e1 = relu_((b1r[1] + w1r[3] * g0 + w1r[4] * g1 + w1r[5] * g2) * sp1 + hp1);
        float e2 = relu_((b1r[2] + w1r[6] * g0 + w1r[7] * g1 + w1r[8] * g2) * sp2 + hp2);
        float pr = bc + wa * e0 + wb * e1 + wcc * e2;
        float wv_ = xk[(size_t)nb * 64 + c] - xq[(size_t)i0 * 64 + c] + pr;
        sum += wv_;
        sq = fmaf(wv_, wv_, sq);
    }
    __shared__ float red[512];
    red[tid] = sum; red[256 + tid] = sq;
    __syncthreads();
    if (tid < 64) {
        float s4 = red[tid] + red[tid + 64] + red[tid + 128] + red[tid + 192];
        float q4 = red[256 + tid] + red[256 + tid + 64] + red[256 + tid + 128] + red[256 + tid + 192];
        part[(size_t)blockIdx.x * 128 + tid] = s4;
        part[(size_t)blockIdx.x * 128 + 64 + tid] = q4;
    }
}

__global__ void k_fin_w0(const float* __restrict__ part, int nbk, float invM,
                         const float* __restrict__ g, const float* __restrict__ b,
                         float* __restrict__ out)
{
    int t = threadIdx.x; // 128
    __shared__ float tot[128];
    float a0 = 0, a1 = 0, a2 = 0, a3 = 0;
    for (int k = 0; k < nbk; k += 4) {
        a0 += part[(size_t)(k + 0) * 128 + t];
        a1 += part[(size_t)(k + 1) * 128 + t];
        a2 += part[(size_t)(k + 2) * 128 + t];
        a3 += part[(size_t)(k + 3) * 128 + t];
    }
    tot[t] = (a0 + a1) + (a2 + a3);
    __syncthreads();
    if (t < 64) {
        float mean = tot[t] * invM;
        float var = tot[64 + t] * invM - mean * mean;
        float sc = g[t] * rsqrtf(var + 1e-5f);
        out[t] = sc;
        out[64 + t] = b[t] - mean * sc;
    }
}

// ---------------- K4: u = relu(bn_w0(w_pre)) @ Ww1.T + bw1, + stats ----------------
__global__ __launch_bounds__(256) void k_u_stats(
    const float* __restrict__ p, const int* __restrict__ idx,
    const float* __restrict__ xq, const float* __restrict__ xk,
    const float* __restrict__ Wp1, const float* __restrict__ bp1,
    const float* __restrict__ bnp,
    const float* __restrict__ Wp2, const float* __restrict__ bp2,
    const float* __restrict__ bnw0,
    const float* __restrict__ Ww1, const float* __restrict__ bw1,
    float* __restrict__ u, float* __restrict__ part, int M)
{
    __shared__ float wp2s[192], bp2s[64], bn0s[128], ww1s[512], bw1s[8];
    int tid = threadIdx.x;
    for (int i = tid; i < 192; i += 256) wp2s[i] = Wp2[i];
    if (tid < 64) bp2s[tid] = bp2[tid];
    if (tid < 128) bn0s[tid] = bnw0[tid];
    for (int i = tid; i < 512; i += 256) ww1s[i] = Ww1[i];
    if (tid < 8) bw1s[tid] = bw1[tid];
    float w1r[9], b1r[3];
    #pragma unroll
    for (int a = 0; a < 9; ++a) w1r[a] = Wp1[a];
    #pragma unroll
    for (int a = 0; a < 3; ++a) b1r[a] = bp1[a];
    float sp0 = bnp[0], sp1 = bnp[1], sp2 = bnp[2];
    float hp0 = bnp[3], hp1 = bnp[4], hp2 = bnp[5];
    __syncthreads();
    float sum[8] = {0,0,0,0,0,0,0,0}, sq[8] = {0,0,0,0,0,0,0,0};
    int step = gridDim.x * 256;
    for (int s = blockIdx.x * 256 + tid; s < M; s += step) {
        int i0 = s >> 4;
        int nb = idx[s];
        float g0 = p[nb * 3 + 0] - p[i0 * 3 + 0];
        float g1 = p[nb * 3 + 1] - p[i0 * 3 + 1];
        float g2 = p[nb * 3 + 2] - p[i0 * 3 + 2];
        float e0 = relu_((b1r[0] + w1r[0] * g0 + w1r[1] * g1 + w1r[2] * g2) * sp0 + hp0);
        float e1 = relu_((b1r[1] + w1r[3] * g0 + w1r[4] * g1 + w1r[5] * g2) * sp1 + hp1);
        float e2 = relu_((b1r[2] + w1r[6] * g0 + w1r[7] * g1 + w1r[8] * g2) * sp2 + hp2);
        float h[64];
        const float4* kr = (const float4*)(xk + (size_t)nb * 64);
        const float4* qr = (const float4*)(xq + (size_t)i0 * 64);
        #pragma unroll
        for (int k4 = 0; k4 < 16; ++k4) {
            float4 kk = kr[k4];
            float4 qq = qr[k4];
            int c = k4 * 4;
            float d0 = kk.x - qq.x, d1 = kk.y - qq.y, d2 = kk.z - qq.z, d3 = kk.w - qq.w;
            h[c + 0] = relu_((d0 + bp2s[c + 0] + wp2s[(c + 0) * 3] * e0 + wp2s[(c + 0) * 3 + 1] * e1 + wp2s[(c + 0) * 3 + 2] * e2) * bn0s[c + 0] + bn0s[64 + c + 0]);
            h[c + 1] = relu_((d1 + bp2s[c + 1] + wp2s[(c + 1) * 3] * e0 + wp2s[(c + 1) * 3 + 1] * e1 + wp2s[(c + 1) * 3 + 2] * e2) * bn0s[c + 1] + bn0s[64 + c + 1]);
            h[c + 2] = relu_((d2 + bp2s[c + 2] + wp2s[(c + 2) * 3] * e0 + wp2s[(c + 2) * 3 + 1] * e1 + wp2s[(c + 2) * 3 + 2] * e2) * bn0s[c + 2] + bn0s[64 + c + 2]);
            h[c + 3] = relu_((d3 + bp2s[c + 3] + wp2s[(c + 3) * 3] * e0 + wp2s[(c + 3) * 3 + 1] * e1 + wp2s[(c + 3) * 3 + 2] * e2) * bn0s[c + 3] + bn0s[64 + c + 3]);
        }
        float uu[8];
        #pragma unroll
        for (int q = 0; q < 8; ++q) {
            float a = bw1s[q];
            #pragma unroll
            for (int k = 0; k < 64; ++k) a = fmaf(ww1s[q * 64 + k], h[k], a);
            uu[q] = a;
            sum[q] += a;
            sq[q] = fmaf(a, a, sq[q]);
        }
        float4* up = (float4*)(u + (size_t)s * 8);
        up[0] = make_float4(uu[0], uu[1], uu[2], uu[3]);
        up[1] = make_float4(uu[4], uu[5], uu[6], uu[7]);
    }
    __shared__ float red4[4][16];
    #pragma unroll
    for (int q = 0; q < 8; ++q) {
        float v = sum[q];
        for (int off = 32; off; off >>= 1) v += __shfl_down(v, off, 64);
        if ((tid & 63) == 0) red4[tid >> 6][q] = v;
        v = sq[q];
        for (int off = 32; off; off >>= 1) v += __shfl_down(v, off, 64);
        if ((tid & 63) == 0) red4[tid >> 6][8 + q] = v;
    }
    __syncthreads();
    if (tid < 16)
        part[(size_t)blockIdx.x * 16 + tid] = red4[0][tid] + red4[1][tid] + red4[2][tid] + red4[3][tid];
}

__global__ void k_fin_w1(const float* __restrict__ part, int nbk, float invM,
                         const float* __restrict__ g, const float* __restrict__ b,
                         float* __restrict__ out)
{
    int t = threadIdx.x; // 16
    __shared__ float tot[16];
    float a0 = 0, a1 = 0, a2 = 0, a3 = 0;
    for (int k = 0; k < nbk; k += 4) {
        a0 += part[(size_t)(k + 0) * 16 + t];
        a1 += part[(size_t)(k + 1) * 16 + t];
        a2 += part[(size_t)(k + 2) * 16 + t];
        a3 += part[(size_t)(k + 3) * 16 + t];
    }
    tot[t] = (a0 + a1) + (a2 + a3);
    __syncthreads();
    if (t < 8) {
        float mean = tot[t] * invM;
        float var = tot[8 + t] * invM - mean * mean;
        float sc = g[t] * rsqrtf(var + 1e-5f);
        out[t] = sc;
        out[8 + t] = b[t] - mean * sc;
    }
}

// ---------------- K5: final weights, softmax, output ----------------
__global__ __launch_bounds__(256) void k_out(
    const float* __restrict__ p, const int* __restrict__ idx,
    const float* __restrict__ xv, const float* __restrict__ u,
    const float* __restrict__ Wp1, const float* __restrict__ bp1,
    const float* __restrict__ bnp,
    const float* __restrict__ Wp2, const float* __restrict__ bp2,
    const float* __restrict__ bnw1,
    const float* __restrict__ Ww2, const float* __restrict__ bw2,
    float* __restrict__ out)
{
    __shared__ float wgt[4][16][8];
    __shared__ float els[4][16][4];
    __shared__ int nbs[4][16];
    int tid = threadIdx.x;
    int lane = tid & 63, wv = tid >> 6;
    size_t i = (size_t)blockIdx.x * 4 + wv;
    if (lane < 16) {
        int j = lane;
        size_t s = i * 16 + j;
        int nb = idx[s];
        nbs[wv][j] = nb;
        float g0 = p[nb * 3 + 0] - p[i * 3 + 0];
        float g1 = p[nb * 3 + 1] - p[i * 3 + 1];
        float g2 = p[nb * 3 + 2] - p[i * 3 + 2];
        float e0 = relu_((bp1[0] + Wp1[0] * g0 + Wp1[1] * g1 + Wp1[2] * g2) * bnp[0] + bnp[3]);
        float e1 = relu_((bp1[1] + Wp1[3] * g0 + Wp1[4] * g1 + Wp1[5] * g2) * bnp[1] + bnp[4]);
        float e2 = relu_((bp1[2] + Wp1[6] * g0 + Wp1[7] * g1 + Wp1[8] * g2) * bnp[2] + bnp[5]);
        els[wv][j][0] = e0; els[wv][j][1] = e1; els[wv][j][2] = e2;
        float4 u0 = ((const float4*)(u + s * 8))[0];
        float4 u1 = ((const float4*)(u + s * 8))[1];
        float r[8];
        r[0] = relu_(u0.x * bnw1[0] + bnw1[8]);
        r[1] = relu_(u0.y * bnw1[1] + bnw1[9]);
        r[2] = relu_(u0.z * bnw1[2] + bnw1[10]);
        r[3] = relu_(u0.w * bnw1[3] + bnw1[11]);
        r[4] = relu_(u1.x * bnw1[4] + bnw1[12]);
        r[5] = relu_(u1.y * bnw1[5] + bnw1[13]);
        r[6] = relu_(u1.z * bnw1[6] + bnw1[14]);
        r[7] = relu_(u1.w * bnw1[7] + bnw1[15]);
        float wrow[8];
        #pragma unroll
        for (int q = 0; q < 8; ++q) {
            float a = bw2[q];
            #pragma unroll
            for (int k = 0; k < 8; ++k) a = fmaf(Ww2[q * 8 + k], r[k], a);
            wrow[q] = a;
        }
        #pragma unroll
        for (int q = 0; q < 8; ++q) {
            float m = wrow[q];
            m = fmaxf(m, __shfl_xor(m, 8, 64));
            m = fmaxf(m, __shfl_xor(m, 4, 64));
            m = fmaxf(m, __shfl_xor(m, 2, 64));
            m = fmaxf(m, __shfl_xor(m, 1, 64));
            float e = __expf(wrow[q] - m);
            float ssum = e;
            ssum += __shfl_xor(ssum, 8, 64);
            ssum += __shfl_xor(ssum, 4, 64);
            ssum += __shfl_xor(ssum, 2, 64);
            ssum += __shfl_xor(ssum, 1, 64);
            wgt[wv][j][q] = e / ssum;
        }
    }
    __syncthreads();
    int c = lane;
    float wa = Wp2[c * 3 + 0], wb = Wp2[c * 3 + 1], wcc = Wp2[c * 3 + 2], bc = bp2[c];
    float acc = 0.f;
    #pragma unroll
    for (int j = 0; j < 16; ++j) {
        int nb = nbs[wv][j];
        float pr = bc + wa * els[wv][j][0] + wb * els[wv][j][1] + wcc * els[wv][j][2];
        float gv = xv[(size_t)nb * 64 + c];
        acc += (gv + pr) * wgt[wv][j][c & 7];
    }
    out[i * 64 + c] = acc;
}

extern "C" void kernel_launch(void* const* d_in, const int* in_sizes, int n_in,
                              void* d_out, int out_size, void* d_ws, size_t ws_size,
                              hipStream_t stream) {
    const float* p    = (const float*)d_in[0];
    const float* x    = (const float*)d_in[1];
    const int*   idx  = (const int*)d_in[2];
    const float* Wq   = (const float*)d_in[3];
    const float* bq   = (const float*)d_in[4];
    const float* Wk   = (const float*)d_in[5];
    const float* bk   = (const float*)d_in[6];
    const float* Wv   = (const float*)d_in[7];
    const float* bv   = (const float*)d_in[8];
    const float* Wp1  = (const float*)d_in[9];
    const float* bp1  = (const float*)d_in[10];
    const float* bnpg = (const float*)d_in[11];
    const float* bnpb = (const float*)d_in[12];
    const float* Wp2  = (const float*)d_in[13];
    const float* bp2  = (const float*)d_in[14];
    const float* bn0g = (const float*)d_in[15];
    const float* bn0b = (const float*)d_in[16];
    const float* Ww1  = (const float*)d_in[17];
    const float* bw1  = (const float*)d_in[18];
    const float* bn1g = (const float*)d_in[19];
    const float* bn1b = (const float*)d_in[20];
    const float* Ww2  = (const float*)d_in[21];
    const float* bw2  = (const float*)d_in[22];

    int n = in_sizes[1] / 64;     // 65536
    int M = n * 16;               // n * ns
    float invM = 1.0f / (float)M;

    // workspace layout (floats)
    float* ws    = (float*)d_ws;
    float* xq    = ws;
    float* xk    = xq + (size_t)n * 64;
    float* xv    = xk + (size_t)n * 64;
    float* u     = xv + (size_t)n * 64;            // n*16*8 floats
    float* part1 = u + (size_t)n * 128;            // NB_STAT*6
    float* part2 = part1 + (size_t)NB_STAT * 6;    // NB_STAT*128
    float* part3 = part2 + (size_t)NB_STAT * 128;  // NB_STAT*16
    float* bnp   = part3 + (size_t)NB_STAT * 16;   // 6 (pad 8)
    float* bnw0  = bnp + 8;                        // 128
    float* bnw1  = bnw0 + 128;                     // 16

    k_proj<<<n / 16, 256, 0, stream>>>(x, Wq, bq, Wk, bk, Wv, bv, xq, xk, xv);
    k_stats_p<<<NB_STAT, 256, 0, stream>>>(p, idx, Wp1, bp1, part1, M);
    k_fin_p<<<1, 64, 0, stream>>>(part1, NB_STAT, invM, bnpg, bnpb, bnp);
    k_stats_w0<<<NB_STAT, 256, 0, stream>>>(p, idx, xq, xk, Wp1, bp1, bnp, Wp2, bp2, part2, M);
    k_fin_w0<<<1, 128, 0, stream>>>(part2, NB_STAT, invM, bn0g, bn0b, bnw0);
    k_u_stats<<<NB_STAT, 256, 0, stream>>>(p, idx, xq, xk, Wp1, bp1, bnp, Wp2, bp2, bnw0, Ww1, bw1, u, part3, M);
    k_fin_w1<<<1, 16, 0, stream>>>(part3, NB_STAT, invM, bn1g, bn1b, bnw1);
    k_out<<<n / 4, 256, 0, stream>>>(p, idx, xv, u, Wp1, bp1, bnp, Wp2, bp2, bnw1, Ww2, bw2, (float*)d_out);
}

// Round 2
// 524.515 us; speedup vs baseline: 1.5676x; 1.5676x over previous
//
#include <hip/hip_runtime.h>
#include <math.h>

// BoundaryTransformerLayer: n=65536 pts, ns=16, C=64, CW=8.
// K1 proj -> K2 p-stats -> fin -> K3 w_pre stats (wave-per-point gather)
// -> fin -> K4 u + stats (thread-per-sample, on-the-fly 64->8 dot)
// -> fin -> K5 softmax + weighted sum (wave-per-point, in-wave softmax)

#define NB_STAT 1024

__device__ __forceinline__ float relu_(float v) { return v > 0.f ? v : 0.f; }

// ---------------- K1: q/k/v projections (unchanged, known-good) ----------------
__global__ __launch_bounds__(256) void k_proj(
    const float* __restrict__ x,
    const float* __restrict__ Wq, const float* __restrict__ bq,
    const float* __restrict__ Wk, const float* __restrict__ bk,
    const float* __restrict__ Wv, const float* __restrict__ bv,
    float* __restrict__ xq, float* __restrict__ xk, float* __restrict__ xv)
{
    __shared__ float wq_s[4096], wk_s[4096], wv_s[4096];   // W^T: [k][c]
    __shared__ float xs[16 * 64];
    __shared__ float bqs[64], bks[64], bvs[64];
    int tid = threadIdx.x;
    for (int i = tid; i < 4096; i += 256) {
        int r = i >> 6, k = i & 63;
        wq_s[k * 64 + r] = Wq[i];
        wk_s[k * 64 + r] = Wk[i];
        wv_s[k * 64 + r] = Wv[i];
    }
    if (tid < 64) { bqs[tid] = bq[tid]; bks[tid] = bk[tid]; bvs[tid] = bv[tid]; }
    size_t base = (size_t)blockIdx.x * 16;
    ((float4*)xs)[tid] = ((const float4*)(x + base * 64))[tid];
    __syncthreads();
    int c = tid & 63, w = tid >> 6;
    float aq[4], ak[4], av[4];
    #pragma unroll
    for (int pp = 0; pp < 4; ++pp) { aq[pp] = bqs[c]; ak[pp] = bks[c]; av[pp] = bvs[c]; }
    const float* xr = &xs[(w * 4) * 64];
    #pragma unroll 4
    for (int k = 0; k < 64; ++k) {
        float wqv = wq_s[k * 64 + c], wkv = wk_s[k * 64 + c], wvv = wv_s[k * 64 + c];
        #pragma unroll
        for (int pp = 0; pp < 4; ++pp) {
            float xv_ = xr[pp * 64 + k];
            aq[pp] = fmaf(xv_, wqv, aq[pp]);
            ak[pp] = fmaf(xv_, wkv, ak[pp]);
            av[pp] = fmaf(xv_, wvv, av[pp]);
        }
    }
    #pragma unroll
    for (int pp = 0; pp < 4; ++pp) {
        size_t pt = base + w * 4 + pp;
        xq[pt * 64 + c] = aq[pp];
        xk[pt * 64 + c] = ak[pp];
        xv[pt * 64 + c] = av[pp];
    }
}

// ---------------- K2: stats of t1 (3 channels) ----------------
__global__ __launch_bounds__(256) void k_stats_p(
    const float* __restrict__ p, const int* __restrict__ idx,
    const float* __restrict__ Wp1, const float* __restrict__ bp1,
    float* __restrict__ part, int M)
{
    int tid = threadIdx.x;
    float w[9], b[3];
    #pragma unroll
    for (int a = 0; a < 9; ++a) w[a] = Wp1[a];
    #pragma unroll
    for (int a = 0; a < 3; ++a) b[a] = bp1[a];
    float s0 = 0, s1 = 0, s2 = 0, q0 = 0, q1 = 0, q2 = 0;
    int step = gridDim.x * 256;
    for (int s = blockIdx.x * 256 + tid; s < M; s += step) {
        int i0 = s >> 4;
        int nb = idx[s];
        float g0 = p[nb * 3 + 0] - p[i0 * 3 + 0];
        float g1 = p[nb * 3 + 1] - p[i0 * 3 + 1];
        float g2 = p[nb * 3 + 2] - p[i0 * 3 + 2];
        float t0 = b[0] + w[0] * g0 + w[1] * g1 + w[2] * g2;
        float t1 = b[1] + w[3] * g0 + w[4] * g1 + w[5] * g2;
        float t2 = b[2] + w[6] * g0 + w[7] * g1 + w[8] * g2;
        s0 += t0; s1 += t1; s2 += t2;
        q0 = fmaf(t0, t0, q0); q1 = fmaf(t1, t1, q1); q2 = fmaf(t2, t2, q2);
    }
    __shared__ float red[4][6];
    float v[6] = { s0, s1, s2, q0, q1, q2 };
    #pragma unroll
    for (int k = 0; k < 6; ++k) {
        float a = v[k];
        for (int off = 32; off; off >>= 1) a += __shfl_down(a, off, 64);
        if ((tid & 63) == 0) red[tid >> 6][k] = a;
    }
    __syncthreads();
    if (tid < 6)
        part[(size_t)blockIdx.x * 6 + tid] = red[0][tid] + red[1][tid] + red[2][tid] + red[3][tid];
}

__global__ void k_fin_p(const float* __restrict__ part, int nbk, float invM,
                        const float* __restrict__ g, const float* __restrict__ b,
                        float* __restrict__ bnp)
{
    int t = threadIdx.x;
    __shared__ float tot[6];
    if (t < 6) {
        float a0 = 0, a1 = 0, a2 = 0, a3 = 0;
        for (int k = 0; k < nbk; k += 4) {
            a0 += part[(size_t)(k + 0) * 6 + t];
            a1 += part[(size_t)(k + 1) * 6 + t];
            a2 += part[(size_t)(k + 2) * 6 + t];
            a3 += part[(size_t)(k + 3) * 6 + t];
        }
        tot[t] = (a0 + a1) + (a2 + a3);
    }
    __syncthreads();
    if (t < 3) {
        float mean = tot[t] * invM;
        float var = tot[3 + t] * invM - mean * mean;
        float sc = g[t] * rsqrtf(var + 1e-5f);
        bnp[t] = sc;
        bnp[3 + t] = b[t] - mean * sc;
    }
}

// ---------------- K3: stats of w_pre, wave-per-point ----------------
__global__ __launch_bounds__(256) void k_stats_w(
    const float* __restrict__ p, const int* __restrict__ idx,
    const float* __restrict__ xq, const float* __restrict__ xk,
    const float* __restrict__ Wp1, const float* __restrict__ bp1,
    const float* __restrict__ bnp,
    const float* __restrict__ Wp2, const float* __restrict__ bp2,
    float* __restrict__ part, int n, int nwaves)
{
    int tid = threadIdx.x, lane = tid & 63;
    int wid = blockIdx.x * 4 + (tid >> 6);
    float wa = Wp2[lane * 3 + 0], wb = Wp2[lane * 3 + 1], wc = Wp2[lane * 3 + 2], bc = bp2[lane];
    float w10 = Wp1[0], w11 = Wp1[1], w12 = Wp1[2];
    float w13 = Wp1[3], w14 = Wp1[4], w15 = Wp1[5];
    float w16 = Wp1[6], w17 = Wp1[7], w18 = Wp1[8];
    float b10 = bp1[0], b11 = bp1[1], b12 = bp1[2];
    float sp0 = bnp[0], sp1 = bnp[1], sp2 = bnp[2];
    float hp0 = bnp[3], hp1 = bnp[4], hp2 = bnp[5];
    float sum = 0.f, sq = 0.f;
    for (int i = wid; i < n; i += nwaves) {
        float pix = p[i * 3 + 0], piy = p[i * 3 + 1], piz = p[i * 3 + 2];
        int nb16 = 0;
        float e0 = 0.f, e1 = 0.f, e2 = 0.f;
        if (lane < 16) {
            nb16 = idx[i * 16 + lane];
            float g0 = p[nb16 * 3 + 0] - pix;
            float g1 = p[nb16 * 3 + 1] - piy;
            float g2 = p[nb16 * 3 + 2] - piz;
            e0 = relu_((b10 + w10 * g0 + w11 * g1 + w12 * g2) * sp0 + hp0);
            e1 = relu_((b11 + w13 * g0 + w14 * g1 + w15 * g2) * sp1 + hp1);
            e2 = relu_((b12 + w16 * g0 + w17 * g1 + w18 * g2) * sp2 + hp2);
        }
        float xqc = xq[(size_t)i * 64 + lane];
        #pragma unroll
        for (int j = 0; j < 16; ++j) {
            int nb = __shfl(nb16, j, 64);
            float f0 = __shfl(e0, j, 64);
            float f1 = __shfl(e1, j, 64);
            float f2 = __shfl(e2, j, 64);
            float pr = bc + wa * f0 + wb * f1 + wc * f2;
            float w = xk[(size_t)nb * 64 + lane] - xqc + pr;
            sum += w;
            sq = fmaf(w, w, sq);
        }
    }
    __shared__ float red[4][2][64];
    red[tid >> 6][0][lane] = sum;
    red[tid >> 6][1][lane] = sq;
    __syncthreads();
    if (tid < 128) {
        int k = tid >> 6, c = tid & 63;
        part[(size_t)blockIdx.x * 128 + tid] =
            red[0][k][c] + red[1][k][c] + red[2][k][c] + red[3][k][c];
    }
}

__global__ void k_fin_w0(const float* __restrict__ part, int nbk, float invM,
                         const float* __restrict__ g, const float* __restrict__ b,
                         float* __restrict__ out)
{
    int t = threadIdx.x; // 128
    __shared__ float tot[128];
    float a0 = 0, a1 = 0, a2 = 0, a3 = 0;
    for (int k = 0; k < nbk; k += 4) {
        a0 += part[(size_t)(k + 0) * 128 + t];
        a1 += part[(size_t)(k + 1) * 128 + t];
        a2 += part[(size_t)(k + 2) * 128 + t];
        a3 += part[(size_t)(k + 3) * 128 + t];
    }
    tot[t] = (a0 + a1) + (a2 + a3);
    __syncthreads();
    if (t < 64) {
        float mean = tot[t] * invM;
        float var = tot[64 + t] * invM - mean * mean;
        float sc = g[t] * rsqrtf(var + 1e-5f);
        out[t] = sc;
        out[64 + t] = b[t] - mean * sc;
    }
}

// ---------------- K4: u = relu(bn_w0(w_pre)) @ Ww1.T + bw1, on-the-fly ----------------
__global__ __launch_bounds__(256) void k_u2(
    const float* __restrict__ p, const int* __restrict__ idx,
    const float* __restrict__ xq, const float* __restrict__ xk,
    const float* __restrict__ Wp1, const float* __restrict__ bp1,
    const float* __restrict__ bnp,
    const float* __restrict__ Wp2, const float* __restrict__ bp2,
    const float* __restrict__ bnw0,
    const float* __restrict__ Ww1, const float* __restrict__ bw1,
    float* __restrict__ u, float* __restrict__ part, int M)
{
    // per-channel folded params: h_c = relu(S*(k-q) + D + A*e0 + B*e1 + C*e2)
    __shared__ float4 sA4[16], sB4[16], sC4[16], sD4[16], sS4[16];
    __shared__ float4 wt4[128];   // [cc*8+q] = Ww1[q][4cc..4cc+3]
    int tid = threadIdx.x;
    if (tid < 64) {
        float sc = bnw0[tid], sh = bnw0[64 + tid];
        float wa = Wp2[tid * 3 + 0], wb = Wp2[tid * 3 + 1], wc = Wp2[tid * 3 + 2], bc = bp2[tid];
        ((float*)sS4)[tid] = sc;
        ((float*)sA4)[tid] = sc * wa;
        ((float*)sB4)[tid] = sc * wb;
        ((float*)sC4)[tid] = sc * wc;
        ((float*)sD4)[tid] = sc * bc + sh;
    }
    for (int t = tid; t < 512; t += 256) {
        int cc = t >> 5, q = (t >> 2) & 7, e = t & 3;
        ((float*)wt4)[t] = Ww1[q * 64 + cc * 4 + e];
    }
    float w10 = Wp1[0], w11 = Wp1[1], w12 = Wp1[2];
    float w13 = Wp1[3], w14 = Wp1[4], w15 = Wp1[5];
    float w16 = Wp1[6], w17 = Wp1[7], w18 = Wp1[8];
    float b10 = bp1[0], b11 = bp1[1], b12 = bp1[2];
    float sp0 = bnp[0], sp1 = bnp[1], sp2 = bnp[2];
    float hp0 = bnp[3], hp1 = bnp[4], hp2 = bnp[5];
    float bw[8];
    #pragma unroll
    for (int q = 0; q < 8; ++q) bw[q] = bw1[q];
    __syncthreads();
    float sum[8] = {0,0,0,0,0,0,0,0}, sq[8] = {0,0,0,0,0,0,0,0};
    int step = gridDim.x * 256;
    for (int s = blockIdx.x * 256 + tid; s < M; s += step) {
        int i0 = s >> 4;
        int nb = idx[s];
        float g0 = p[nb * 3 + 0] - p[i0 * 3 + 0];
        float g1 = p[nb * 3 + 1] - p[i0 * 3 + 1];
        float g2 = p[nb * 3 + 2] - p[i0 * 3 + 2];
        float e0 = relu_((b10 + w10 * g0 + w11 * g1 + w12 * g2) * sp0 + hp0);
        float e1 = relu_((b11 + w13 * g0 + w14 * g1 + w15 * g2) * sp1 + hp1);
        float e2 = relu_((b12 + w16 * g0 + w17 * g1 + w18 * g2) * sp2 + hp2);
        const float4* kr = (const float4*)(xk + (size_t)nb * 64);
        const float4* qr = (const float4*)(xq + (size_t)i0 * 64);
        float acc[8];
        #pragma unroll
        for (int q = 0; q < 8; ++q) acc[q] = bw[q];
        #pragma unroll 4
        for (int cc = 0; cc < 16; ++cc) {
            float4 kk = kr[cc], qv = qr[cc];
            float4 A = sA4[cc], B = sB4[cc], C = sC4[cc], D = sD4[cc], S = sS4[cc];
            float t0 = fmaf(A.x, e0, D.x); t0 = fmaf(B.x, e1, t0); t0 = fmaf(C.x, e2, t0);
            float h0 = relu_(fmaf(S.x, kk.x - qv.x, t0));
            float t1 = fmaf(A.y, e0, D.y); t1 = fmaf(B.y, e1, t1); t1 = fmaf(C.y, e2, t1);
            float h1 = relu_(fmaf(S.y, kk.y - qv.y, t1));
            float t2 = fmaf(A.z, e0, D.z); t2 = fmaf(B.z, e1, t2); t2 = fmaf(C.z, e2, t2);
            float h2 = relu_(fmaf(S.z, kk.z - qv.z, t2));
            float t3 = fmaf(A.w, e0, D.w); t3 = fmaf(B.w, e1, t3); t3 = fmaf(C.w, e2, t3);
            float h3 = relu_(fmaf(S.w, kk.w - qv.w, t3));
            #pragma unroll
            for (int q = 0; q < 8; ++q) {
                float4 ww = wt4[cc * 8 + q];
                acc[q] = fmaf(ww.x, h0, acc[q]);
                acc[q] = fmaf(ww.y, h1, acc[q]);
                acc[q] = fmaf(ww.z, h2, acc[q]);
                acc[q] = fmaf(ww.w, h3, acc[q]);
            }
        }
        float4* up = (float4*)(u + (size_t)s * 8);
        up[0] = make_float4(acc[0], acc[1], acc[2], acc[3]);
        up[1] = make_float4(acc[4], acc[5], acc[6], acc[7]);
        #pragma unroll
        for (int q = 0; q < 8; ++q) {
            sum[q] += acc[q];
            sq[q] = fmaf(acc[q], acc[q], sq[q]);
        }
    }
    __shared__ float red4[4][16];
    #pragma unroll
    for (int q = 0; q < 8; ++q) {
        float v = sum[q];
        for (int off = 32; off; off >>= 1) v += __shfl_down(v, off, 64);
        if ((tid & 63) == 0) red4[tid >> 6][q] = v;
        v = sq[q];
        for (int off = 32; off; off >>= 1) v += __shfl_down(v, off, 64);
        if ((tid & 63) == 0) red4[tid >> 6][8 + q] = v;
    }
    __syncthreads();
    if (tid < 16)
        part[(size_t)blockIdx.x * 16 + tid] = red4[0][tid] + red4[1][tid] + red4[2][tid] + red4[3][tid];
}

__global__ void k_fin_w1(const float* __restrict__ part, int nbk, float invM,
                         const float* __restrict__ g, const float* __restrict__ b,
                         float* __restrict__ out)
{
    int t = threadIdx.x; // 16
    __shared__ float tot[16];
    float a0 = 0, a1 = 0, a2 = 0, a3 = 0;
    for (int k = 0; k < nbk; k += 4) {
        a0 += part[(size_t)(k + 0) * 16 + t];
        a1 += part[(size_t)(k + 1) * 16 + t];
        a2 += part[(size_t)(k + 2) * 16 + t];
        a3 += part[(size_t)(k + 3) * 16 + t];
    }
    tot[t] = (a0 + a1) + (a2 + a3);
    __syncthreads();
    if (t < 8) {
        float mean = tot[t] * invM;
        float var = tot[8 + t] * invM - mean * mean;
        float sc = g[t] * rsqrtf(var + 1e-5f);
        out[t] = sc;
        out[8 + t] = b[t] - mean * sc;
    }
}

// ---------------- K5: softmax + weighted sum, wave-per-point ----------------
__global__ __launch_bounds__(256) void k_out2(
    const float* __restrict__ p, const int* __restrict__ idx,
    const float* __restrict__ xv, const float* __restrict__ u,
    const float* __restrict__ Wp1, const float* __restrict__ bp1,
    const float* __restrict__ bnp,
    const float* __restrict__ Wp2, const float* __restrict__ bp2,
    const float* __restrict__ bnw1,
    const float* __restrict__ Ww2, const float* __restrict__ bw2,
    float* __restrict__ out, int n, int nwaves)
{
    int tid = threadIdx.x, lane = tid & 63;
    int wid = blockIdx.x * 4 + (tid >> 6);
    int qq = lane & 7;
    float wa = Wp2[lane * 3 + 0], wb = Wp2[lane * 3 + 1], wc = Wp2[lane * 3 + 2], bc = bp2[lane];
    float s1 = bnw1[qq], h1 = bnw1[8 + qq];
    float w2r[8];
    #pragma unroll
    for (int k = 0; k < 8; ++k) w2r[k] = Ww2[qq * 8 + k];
    float bz = bw2[qq];
    float w10 = Wp1[0], w11 = Wp1[1], w12 = Wp1[2];
    float w13 = Wp1[3], w14 = Wp1[4], w15 = Wp1[5];
    float w16 = Wp1[6], w17 = Wp1[7], w18 = Wp1[8];
    float b10 = bp1[0], b11 = bp1[1], b12 = bp1[2];
    float sp0 = bnp[0], sp1 = bnp[1], sp2 = bnp[2];
    float hp0 = bnp[3], hp1 = bnp[4], hp2 = bnp[5];
    for (int i = wid; i < n; i += nwaves) {
        // u element (j,q): lane holds j=lane>>3 (reg1) and j=8+(lane>>3) (reg2), q=lane&7
        float u1 = u[(size_t)i * 128 + lane];
        float u2 = u[(size_t)i * 128 + 64 + lane];
        float r1 = relu_(fmaf(u1, s1, h1));
        float r2 = relu_(fmaf(u2, s1, h1));
        int base = lane & 56;
        float z1 = bz, z2 = bz;
        #pragma unroll
        for (int k = 0; k < 8; ++k) {
            z1 = fmaf(w2r[k], __shfl(r1, base + k, 64), z1);
            z2 = fmaf(w2r[k], __shfl(r2, base + k, 64), z2);
        }
        // softmax over 16 neighbors (same q = same lane&7: xor lanes 8,16,32 + local pair)
        float m = fmaxf(z1, z2);
        m = fmaxf(m, __shfl_xor(m, 8, 64));
        m = fmaxf(m, __shfl_xor(m, 16, 64));
        m = fmaxf(m, __shfl_xor(m, 32, 64));
        float p1 = __expf(z1 - m), p2 = __expf(z2 - m);
        float se = p1 + p2;
        se += __shfl_xor(se, 8, 64);
        se += __shfl_xor(se, 16, 64);
        se += __shfl_xor(se, 32, 64);
        float inv = 1.0f / se;
        float wt1 = p1 * inv, wt2 = p2 * inv;
        // accumulate output: lane = channel c
        float pix = p[i * 3 + 0], piy = p[i * 3 + 1], piz = p[i * 3 + 2];
        int nb16 = (lane < 16) ? idx[i * 16 + lane] : 0;
        float acc = 0.f;
        #pragma unroll
        for (int j = 0; j < 16; ++j) {
            int nb = __shfl(nb16, j, 64);
            float g0 = p[nb * 3 + 0] - pix;
            float g1 = p[nb * 3 + 1] - piy;
            float g2 = p[nb * 3 + 2] - piz;
            float e0 = relu_((b10 + w10 * g0 + w11 * g1 + w12 * g2) * sp0 + hp0);
            float e1 = relu_((b11 + w13 * g0 + w14 * g1 + w15 * g2) * sp1 + hp1);
            float e2 = relu_((b12 + w16 * g0 + w17 * g1 + w18 * g2) * sp2 + hp2);
            float pr = bc + wa * e0 + wb * e1 + wc * e2;
            float wgt = __shfl(j < 8 ? wt1 : wt2, ((j & 7) << 3) + qq, 64);
            acc = fmaf(xv[(size_t)nb * 64 + lane] + pr, wgt, acc);
        }
        out[(size_t)i * 64 + lane] = acc;
    }
}

extern "C" void kernel_launch(void* const* d_in, const int* in_sizes, int n_in,
                              void* d_out, int out_size, void* d_ws, size_t ws_size,
                              hipStream_t stream) {
    const float* p    = (const float*)d_in[0];
    const float* x    = (const float*)d_in[1];
    const int*   idx  = (const int*)d_in[2];
    const float* Wq   = (const float*)d_in[3];
    const float* bq   = (const float*)d_in[4];
    const float* Wk   = (const float*)d_in[5];
    const float* bk   = (const float*)d_in[6];
    const float* Wv   = (const float*)d_in[7];
    const float* bv   = (const float*)d_in[8];
    const float* Wp1  = (const float*)d_in[9];
    const float* bp1  = (const float*)d_in[10];
    const float* bnpg = (const float*)d_in[11];
    const float* bnpb = (const float*)d_in[12];
    const float* Wp2  = (const float*)d_in[13];
    const float* bp2  = (const float*)d_in[14];
    const float* bn0g = (const float*)d_in[15];
    const float* bn0b = (const float*)d_in[16];
    const float* Ww1  = (const float*)d_in[17];
    const float* bw1  = (const float*)d_in[18];
    const float* bn1g = (const float*)d_in[19];
    const float* bn1b = (const float*)d_in[20];
    const float* Ww2  = (const float*)d_in[21];
    const float* bw2  = (const float*)d_in[22];

    int n = in_sizes[1] / 64;     // 65536
    int M = n * 16;               // n * ns
    float invM = 1.0f / (float)M;

    // workspace layout (floats) — identical footprint to the passing round
    float* ws    = (float*)d_ws;
    float* xq    = ws;
    float* xk    = xq + (size_t)n * 64;
    float* xv    = xk + (size_t)n * 64;
    float* u     = xv + (size_t)n * 64;            // n*16*8 floats
    float* part1 = u + (size_t)n * 128;            // NB_STAT*6
    float* part2 = part1 + (size_t)NB_STAT * 6;    // NB_STAT*128
    float* part3 = part2 + (size_t)NB_STAT * 128;  // NB_STAT*16
    float* bnp   = part3 + (size_t)NB_STAT * 16;   // 6 (pad 8)
    float* bnw0  = bnp + 8;                        // 128
    float* bnw1  = bnw0 + 128;                     // 16

    k_proj<<<n / 16, 256, 0, stream>>>(x, Wq, bq, Wk, bk, Wv, bv, xq, xk, xv);
    k_stats_p<<<NB_STAT, 256, 0, stream>>>(p, idx, Wp1, bp1, part1, M);
    k_fin_p<<<1, 64, 0, stream>>>(part1, NB_STAT, invM, bnpg, bnpb, bnp);
    k_stats_w<<<NB_STAT, 256, 0, stream>>>(p, idx, xq, xk, Wp1, bp1, bnp, Wp2, bp2, part2, n, NB_STAT * 4);
    k_fin_w0<<<1, 128, 0, stream>>>(part2, NB_STAT, invM, bn0g, bn0b, bnw0);
    k_u2<<<NB_STAT, 256, 0, stream>>>(p, idx, xq, xk, Wp1, bp1, bnp, Wp2, bp2, bnw0, Ww1, bw1, u, part3, M);
    k_fin_w1<<<1, 16, 0, stream>>>(part3, NB_STAT, invM, bn1g, bn1b, bnw1);
    k_out2<<<2048, 256, 0, stream>>>(p, idx, xv, u, Wp1, bp1, bnp, Wp2, bp2, bnw1, Ww2, bw2, (float*)d_out, n, 2048 * 4);
}

// Round 3
// 428.081 us; speedup vs baseline: 1.9207x; 1.2253x over previous
//
#include <hip/hip_runtime.h>
#include <math.h>

// BoundaryTransformerLayer: n=65536 pts, ns=16, C=64, CW=8.
// K1 proj (bf16-packed outputs) -> K2 p-stats -> fin -> K3 w_pre stats
// -> fin -> K4 u (bf16) + stats -> fin -> K5 softmax + weighted sum.
// All gather rows are 128B bf16-packed (2 ch per uint32).

#define NB_STAT 1024

__device__ __forceinline__ float relu_(float v) { return v > 0.f ? v : 0.f; }

__device__ __forceinline__ unsigned pack_bf16(float a, float b) {
    unsigned ua = __float_as_uint(a);
    ua = (ua + 0x7FFFu + ((ua >> 16) & 1u)) >> 16;
    unsigned ub = __float_as_uint(b);
    ub = (ub + 0x7FFFu + ((ub >> 16) & 1u)) >> 16;
    return ua | (ub << 16);
}
__device__ __forceinline__ float ubf(unsigned u, int hi) {
    return __uint_as_float(hi ? (u & 0xFFFF0000u) : (u << 16));
}
__device__ __forceinline__ float ublo(unsigned u) { return __uint_as_float(u << 16); }
__device__ __forceinline__ float ubhi(unsigned u) { return __uint_as_float(u & 0xFFFF0000u); }

// ---------------- K1: q/k/v projections, bf16-packed output ----------------
__global__ __launch_bounds__(256) void k_proj2(
    const float* __restrict__ x,
    const float* __restrict__ Wq, const float* __restrict__ bq,
    const float* __restrict__ Wk, const float* __restrict__ bk,
    const float* __restrict__ Wv, const float* __restrict__ bv,
    unsigned* __restrict__ xqh, unsigned* __restrict__ xkh, unsigned* __restrict__ xvh)
{
    // wq4[kk*64+c] = {W[c][4kk..4kk+3]}  (k-grouped, conflict-free reads/writes)
    __shared__ float4 wq4[1024], wk4[1024], wv4[1024];
    __shared__ float4 xs4[512];            // [pt*16+kk]
    __shared__ float bqs[64], bks[64], bvs[64];
    int tid = threadIdx.x;
    for (int i = tid; i < 1024; i += 256) {
        int c = i & 63, kk = i >> 6;
        wq4[kk * 64 + c] = ((const float4*)Wq)[c * 16 + kk];
        wk4[kk * 64 + c] = ((const float4*)Wk)[c * 16 + kk];
        wv4[kk * 64 + c] = ((const float4*)Wv)[c * 16 + kk];
    }
    if (tid < 64) { bqs[tid] = bq[tid]; bks[tid] = bk[tid]; bvs[tid] = bv[tid]; }
    size_t base = (size_t)blockIdx.x * 32;
    for (int i = tid; i < 512; i += 256)
        xs4[i] = ((const float4*)(x + base * 64))[i];
    __syncthreads();
    int c = tid & 63, w = tid >> 6;
    float aq[8], ak[8], av[8];
    #pragma unroll
    for (int pp = 0; pp < 8; ++pp) { aq[pp] = bqs[c]; ak[pp] = bks[c]; av[pp] = bvs[c]; }
    #pragma unroll 4
    for (int kk = 0; kk < 16; ++kk) {
        float4 q4 = wq4[kk * 64 + c];
        float4 k4 = wk4[kk * 64 + c];
        float4 v4 = wv4[kk * 64 + c];
        #pragma unroll
        for (int pp = 0; pp < 8; ++pp) {
            float4 xv4 = xs4[(w * 8 + pp) * 16 + kk];
            aq[pp] = fmaf(xv4.x, q4.x, aq[pp]); aq[pp] = fmaf(xv4.y, q4.y, aq[pp]);
            aq[pp] = fmaf(xv4.z, q4.z, aq[pp]); aq[pp] = fmaf(xv4.w, q4.w, aq[pp]);
            ak[pp] = fmaf(xv4.x, k4.x, ak[pp]); ak[pp] = fmaf(xv4.y, k4.y, ak[pp]);
            ak[pp] = fmaf(xv4.z, k4.z, ak[pp]); ak[pp] = fmaf(xv4.w, k4.w, ak[pp]);
            av[pp] = fmaf(xv4.x, v4.x, av[pp]); av[pp] = fmaf(xv4.y, v4.y, av[pp]);
            av[pp] = fmaf(xv4.z, v4.z, av[pp]); av[pp] = fmaf(xv4.w, v4.w, av[pp]);
        }
    }
    #pragma unroll
    for (int pp = 0; pp < 8; ++pp) {
        size_t pt = base + w * 8 + pp;
        float hq = __shfl_down(aq[pp], 1, 64);
        float hk = __shfl_down(ak[pp], 1, 64);
        float hv = __shfl_down(av[pp], 1, 64);
        if ((c & 1) == 0) {
            xqh[pt * 32 + (c >> 1)] = pack_bf16(aq[pp], hq);
            xkh[pt * 32 + (c >> 1)] = pack_bf16(ak[pp], hk);
            xvh[pt * 32 + (c >> 1)] = pack_bf16(av[pp], hv);
        }
    }
}

// ---------------- K2: stats of t1 (3 channels) ----------------
__global__ __launch_bounds__(256) void k_stats_p(
    const float* __restrict__ p, const int* __restrict__ idx,
    const float* __restrict__ Wp1, const float* __restrict__ bp1,
    float* __restrict__ part, int M)
{
    int tid = threadIdx.x;
    float w[9], b[3];
    #pragma unroll
    for (int a = 0; a < 9; ++a) w[a] = Wp1[a];
    #pragma unroll
    for (int a = 0; a < 3; ++a) b[a] = bp1[a];
    float s0 = 0, s1 = 0, s2 = 0, q0 = 0, q1 = 0, q2 = 0;
    int step = gridDim.x * 256;
    for (int s = blockIdx.x * 256 + tid; s < M; s += step) {
        int i0 = s >> 4;
        int nb = idx[s];
        float g0 = p[nb * 3 + 0] - p[i0 * 3 + 0];
        float g1 = p[nb * 3 + 1] - p[i0 * 3 + 1];
        float g2 = p[nb * 3 + 2] - p[i0 * 3 + 2];
        float t0 = b[0] + w[0] * g0 + w[1] * g1 + w[2] * g2;
        float t1 = b[1] + w[3] * g0 + w[4] * g1 + w[5] * g2;
        float t2 = b[2] + w[6] * g0 + w[7] * g1 + w[8] * g2;
        s0 += t0; s1 += t1; s2 += t2;
        q0 = fmaf(t0, t0, q0); q1 = fmaf(t1, t1, q1); q2 = fmaf(t2, t2, q2);
    }
    __shared__ float red[4][6];
    float v[6] = { s0, s1, s2, q0, q1, q2 };
    #pragma unroll
    for (int k = 0; k < 6; ++k) {
        float a = v[k];
        for (int off = 32; off; off >>= 1) a += __shfl_down(a, off, 64);
        if ((tid & 63) == 0) red[tid >> 6][k] = a;
    }
    __syncthreads();
    if (tid < 6)
        part[(size_t)blockIdx.x * 6 + tid] = red[0][tid] + red[1][tid] + red[2][tid] + red[3][tid];
}

__global__ void k_fin_p(const float* __restrict__ part, int nbk, float invM,
                        const float* __restrict__ g, const float* __restrict__ b,
                        float* __restrict__ bnp)
{
    int t = threadIdx.x;
    __shared__ float tot[6];
    if (t < 6) {
        float a0 = 0, a1 = 0, a2 = 0, a3 = 0;
        for (int k = 0; k < nbk; k += 4) {
            a0 += part[(size_t)(k + 0) * 6 + t];
            a1 += part[(size_t)(k + 1) * 6 + t];
            a2 += part[(size_t)(k + 2) * 6 + t];
            a3 += part[(size_t)(k + 3) * 6 + t];
        }
        tot[t] = (a0 + a1) + (a2 + a3);
    }
    __syncthreads();
    if (t < 3) {
        float mean = tot[t] * invM;
        float var = tot[3 + t] * invM - mean * mean;
        float sc = g[t] * rsqrtf(var + 1e-5f);
        bnp[t] = sc;
        bnp[3 + t] = b[t] - mean * sc;
    }
}

// ---------------- K3: stats of w_pre, wave-per-point, bf16 gathers ----------------
__global__ __launch_bounds__(256) void k_stats_w(
    const float* __restrict__ p, const int* __restrict__ idx,
    const unsigned* __restrict__ xqh, const unsigned* __restrict__ xkh,
    const float* __restrict__ Wp1, const float* __restrict__ bp1,
    const float* __restrict__ bnp,
    const float* __restrict__ Wp2, const float* __restrict__ bp2,
    float* __restrict__ part, int n, int nwaves)
{
    int tid = threadIdx.x, lane = tid & 63;
    int wid = blockIdx.x * 4 + (tid >> 6);
    int sel = lane & 1;
    float wa = Wp2[lane * 3 + 0], wb = Wp2[lane * 3 + 1], wc = Wp2[lane * 3 + 2], bc = bp2[lane];
    float w10 = Wp1[0], w11 = Wp1[1], w12 = Wp1[2];
    float w13 = Wp1[3], w14 = Wp1[4], w15 = Wp1[5];
    float w16 = Wp1[6], w17 = Wp1[7], w18 = Wp1[8];
    float b10 = bp1[0], b11 = bp1[1], b12 = bp1[2];
    float sp0 = bnp[0], sp1 = bnp[1], sp2 = bnp[2];
    float hp0 = bnp[3], hp1 = bnp[4], hp2 = bnp[5];
    float sum = 0.f, sq = 0.f;
    for (int i = wid; i < n; i += nwaves) {
        float pix = p[i * 3 + 0], piy = p[i * 3 + 1], piz = p[i * 3 + 2];
        int nb16 = 0;
        float e0 = 0.f, e1 = 0.f, e2 = 0.f;
        if (lane < 16) {
            nb16 = idx[i * 16 + lane];
            float g0 = p[nb16 * 3 + 0] - pix;
            float g1 = p[nb16 * 3 + 1] - piy;
            float g2 = p[nb16 * 3 + 2] - piz;
            e0 = relu_((b10 + w10 * g0 + w11 * g1 + w12 * g2) * sp0 + hp0);
            e1 = relu_((b11 + w13 * g0 + w14 * g1 + w15 * g2) * sp1 + hp1);
            e2 = relu_((b12 + w16 * g0 + w17 * g1 + w18 * g2) * sp2 + hp2);
        }
        float xqc = ubf(xqh[(size_t)i * 32 + (lane >> 1)], sel);
        #pragma unroll
        for (int j = 0; j < 16; ++j) {
            int nb = __shfl(nb16, j, 64);
            float f0 = __shfl(e0, j, 64);
            float f1 = __shfl(e1, j, 64);
            float f2 = __shfl(e2, j, 64);
            float pr = bc + wa * f0 + wb * f1 + wc * f2;
            float kv = ubf(xkh[(size_t)nb * 32 + (lane >> 1)], sel);
            float w = kv - xqc + pr;
            sum += w;
            sq = fmaf(w, w, sq);
        }
    }
    __shared__ float red[4][2][64];
    red[tid >> 6][0][lane] = sum;
    red[tid >> 6][1][lane] = sq;
    __syncthreads();
    if (tid < 128) {
        int k = tid >> 6, c = tid & 63;
        part[(size_t)blockIdx.x * 128 + tid] =
            red[0][k][c] + red[1][k][c] + red[2][k][c] + red[3][k][c];
    }
}

__global__ void k_fin_w0(const float* __restrict__ part, int nbk, float invM,
                         const float* __restrict__ g, const float* __restrict__ b,
                         float* __restrict__ out)
{
    int t = threadIdx.x; // 128
    __shared__ float tot[128];
    float a0 = 0, a1 = 0, a2 = 0, a3 = 0;
    for (int k = 0; k < nbk; k += 4) {
        a0 += part[(size_t)(k + 0) * 128 + t];
        a1 += part[(size_t)(k + 1) * 128 + t];
        a2 += part[(size_t)(k + 2) * 128 + t];
        a3 += part[(size_t)(k + 3) * 128 + t];
    }
    tot[t] = (a0 + a1) + (a2 + a3);
    __syncthreads();
    if (t < 64) {
        float mean = tot[t] * invM;
        float var = tot[64 + t] * invM - mean * mean;
        float sc = g[t] * rsqrtf(var + 1e-5f);
        out[t] = sc;
        out[64 + t] = b[t] - mean * sc;
    }
}

// ---------------- K4: u = relu(bn_w0(w_pre)) @ Ww1.T + bw1 (bf16 in/out) ----------------
__global__ __launch_bounds__(256) void k_u2(
    const float* __restrict__ p, const int* __restrict__ idx,
    const unsigned* __restrict__ xqh, const unsigned* __restrict__ xkh,
    const float* __restrict__ Wp1, const float* __restrict__ bp1,
    const float* __restrict__ bnp,
    const float* __restrict__ Wp2, const float* __restrict__ bp2,
    const float* __restrict__ bnw0,
    const float* __restrict__ Ww1, const float* __restrict__ bw1,
    unsigned* __restrict__ uh, float* __restrict__ part, int M)
{
    // per-channel folded: h_c = relu(S*(k-q) + D + A*e0 + B*e1 + C*e2)
    __shared__ float4 sA4[16], sB4[16], sC4[16], sD4[16], sS4[16];
    __shared__ float4 wt4[128];   // [cc*8+q] = Ww1[q][4cc..4cc+3]
    int tid = threadIdx.x;
    if (tid < 64) {
        float sc = bnw0[tid], sh = bnw0[64 + tid];
        float wa = Wp2[tid * 3 + 0], wb = Wp2[tid * 3 + 1], wc = Wp2[tid * 3 + 2], bc = bp2[tid];
        ((float*)sS4)[tid] = sc;
        ((float*)sA4)[tid] = sc * wa;
        ((float*)sB4)[tid] = sc * wb;
        ((float*)sC4)[tid] = sc * wc;
        ((float*)sD4)[tid] = sc * bc + sh;
    }
    for (int t = tid; t < 512; t += 256) {
        int cc = t >> 5, q = (t >> 2) & 7, e = t & 3;
        ((float*)wt4)[t] = Ww1[q * 64 + cc * 4 + e];
    }
    float w10 = Wp1[0], w11 = Wp1[1], w12 = Wp1[2];
    float w13 = Wp1[3], w14 = Wp1[4], w15 = Wp1[5];
    float w16 = Wp1[6], w17 = Wp1[7], w18 = Wp1[8];
    float b10 = bp1[0], b11 = bp1[1], b12 = bp1[2];
    float sp0 = bnp[0], sp1 = bnp[1], sp2 = bnp[2];
    float hp0 = bnp[3], hp1 = bnp[4], hp2 = bnp[5];
    float bw[8];
    #pragma unroll
    for (int q = 0; q < 8; ++q) bw[q] = bw1[q];
    __syncthreads();
    float sum[8] = {0,0,0,0,0,0,0,0}, sq[8] = {0,0,0,0,0,0,0,0};
    int step = gridDim.x * 256;
    for (int s = blockIdx.x * 256 + tid; s < M; s += step) {
        int i0 = s >> 4;
        int nb = idx[s];
        float g0 = p[nb * 3 + 0] - p[i0 * 3 + 0];
        float g1 = p[nb * 3 + 1] - p[i0 * 3 + 1];
        float g2 = p[nb * 3 + 2] - p[i0 * 3 + 2];
        float e0 = relu_((b10 + w10 * g0 + w11 * g1 + w12 * g2) * sp0 + hp0);
        float e1 = relu_((b11 + w13 * g0 + w14 * g1 + w15 * g2) * sp1 + hp1);
        float e2 = relu_((b12 + w16 * g0 + w17 * g1 + w18 * g2) * sp2 + hp2);
        const uint2* krh = (const uint2*)(xkh + (size_t)nb * 32);
        const uint2* qrh = (const uint2*)(xqh + (size_t)i0 * 32);
        float acc[8];
        #pragma unroll
        for (int q = 0; q < 8; ++q) acc[q] = bw[q];
        #pragma unroll 4
        for (int cc = 0; cc < 16; ++cc) {
            uint2 uk = krh[cc], uq = qrh[cc];
            float d0 = ublo(uk.x) - ublo(uq.x);
            float d1 = ubhi(uk.x) - ubhi(uq.x);
            float d2 = ublo(uk.y) - ublo(uq.y);
            float d3 = ubhi(uk.y) - ubhi(uq.y);
            float4 A = sA4[cc], B = sB4[cc], C = sC4[cc], D = sD4[cc], S = sS4[cc];
            float t0 = fmaf(A.x, e0, D.x); t0 = fmaf(B.x, e1, t0); t0 = fmaf(C.x, e2, t0);
            float h0 = relu_(fmaf(S.x, d0, t0));
            float t1 = fmaf(A.y, e0, D.y); t1 = fmaf(B.y, e1, t1); t1 = fmaf(C.y, e2, t1);
            float h1 = relu_(fmaf(S.y, d1, t1));
            float t2 = fmaf(A.z, e0, D.z); t2 = fmaf(B.z, e1, t2); t2 = fmaf(C.z, e2, t2);
            float h2 = relu_(fmaf(S.z, d2, t2));
            float t3 = fmaf(A.w, e0, D.w); t3 = fmaf(B.w, e1, t3); t3 = fmaf(C.w, e2, t3);
            float h3 = relu_(fmaf(S.w, d3, t3));
            #pragma unroll
            for (int q = 0; q < 8; ++q) {
                float4 ww = wt4[cc * 8 + q];
                acc[q] = fmaf(ww.x, h0, acc[q]);
                acc[q] = fmaf(ww.y, h1, acc[q]);
                acc[q] = fmaf(ww.z, h2, acc[q]);
                acc[q] = fmaf(ww.w, h3, acc[q]);
            }
        }
        ((uint4*)(uh + (size_t)s * 4))[0] = make_uint4(
            pack_bf16(acc[0], acc[1]), pack_bf16(acc[2], acc[3]),
            pack_bf16(acc[4], acc[5]), pack_bf16(acc[6], acc[7]));
        #pragma unroll
        for (int q = 0; q < 8; ++q) {
            sum[q] += acc[q];
            sq[q] = fmaf(acc[q], acc[q], sq[q]);
        }
    }
    __shared__ float red4[4][16];
    #pragma unroll
    for (int q = 0; q < 8; ++q) {
        float v = sum[q];
        for (int off = 32; off; off >>= 1) v += __shfl_down(v, off, 64);
        if ((tid & 63) == 0) red4[tid >> 6][q] = v;
        v = sq[q];
        for (int off = 32; off; off >>= 1) v += __shfl_down(v, off, 64);
        if ((tid & 63) == 0) red4[tid >> 6][8 + q] = v;
    }
    __syncthreads();
    if (tid < 16)
        part[(size_t)blockIdx.x * 16 + tid] = red4[0][tid] + red4[1][tid] + red4[2][tid] + red4[3][tid];
}

__global__ void k_fin_w1(const float* __restrict__ part, int nbk, float invM,
                         const float* __restrict__ g, const float* __restrict__ b,
                         float* __restrict__ out)
{
    int t = threadIdx.x; // 16
    __shared__ float tot[16];
    float a0 = 0, a1 = 0, a2 = 0, a3 = 0;
    for (int k = 0; k < nbk; k += 4) {
        a0 += part[(size_t)(k + 0) * 16 + t];
        a1 += part[(size_t)(k + 1) * 16 + t];
        a2 += part[(size_t)(k + 2) * 16 + t];
        a3 += part[(size_t)(k + 3) * 16 + t];
    }
    tot[t] = (a0 + a1) + (a2 + a3);
    __syncthreads();
    if (t < 8) {
        float mean = tot[t] * invM;
        float var = tot[8 + t] * invM - mean * mean;
        float sc = g[t] * rsqrtf(var + 1e-5f);
        out[t] = sc;
        out[8 + t] = b[t] - mean * sc;
    }
}

// ---------------- K5: softmax + weighted sum, wave-per-point ----------------
__global__ __launch_bounds__(256) void k_out2(
    const float* __restrict__ p, const int* __restrict__ idx,
    const unsigned* __restrict__ xvh, const unsigned* __restrict__ uh,
    const float* __restrict__ Wp1, const float* __restrict__ bp1,
    const float* __restrict__ bnp,
    const float* __restrict__ Wp2, const float* __restrict__ bp2,
    const float* __restrict__ bnw1,
    const float* __restrict__ Ww2, const float* __restrict__ bw2,
    float* __restrict__ out, int n, int nwaves)
{
    int tid = threadIdx.x, lane = tid & 63;
    int wid = blockIdx.x * 4 + (tid >> 6);
    int qq = lane & 7, sel = lane & 1;
    float wa = Wp2[lane * 3 + 0], wb = Wp2[lane * 3 + 1], wc = Wp2[lane * 3 + 2], bc = bp2[lane];
    float s1 = bnw1[qq], h1 = bnw1[8 + qq];
    float w2r[8];
    #pragma unroll
    for (int k = 0; k < 8; ++k) w2r[k] = Ww2[qq * 8 + k];
    float bz = bw2[qq];
    float w10 = Wp1[0], w11 = Wp1[1], w12 = Wp1[2];
    float w13 = Wp1[3], w14 = Wp1[4], w15 = Wp1[5];
    float w16 = Wp1[6], w17 = Wp1[7], w18 = Wp1[8];
    float b10 = bp1[0], b11 = bp1[1], b12 = bp1[2];
    float sp0 = bnp[0], sp1 = bnp[1], sp2 = bnp[2];
    float hp0 = bnp[3], hp1 = bnp[4], hp2 = bnp[5];
    for (int i = wid; i < n; i += nwaves) {
        // u element (j,q): lane holds j=lane>>3 (u1) and 8+(lane>>3) (u2), q=lane&7
        float u1 = ubf(uh[(size_t)i * 64 + (lane >> 1)], sel);
        float u2 = ubf(uh[(size_t)i * 64 + 32 + (lane >> 1)], sel);
        float r1 = relu_(fmaf(u1, s1, h1));
        float r2 = relu_(fmaf(u2, s1, h1));
        int base = lane & 56;
        float z1 = bz, z2 = bz;
        #pragma unroll
        for (int k = 0; k < 8; ++k) {
            z1 = fmaf(w2r[k], __shfl(r1, base + k, 64), z1);
            z2 = fmaf(w2r[k], __shfl(r2, base + k, 64), z2);
        }
        float m = fmaxf(z1, z2);
        m = fmaxf(m, __shfl_xor(m, 8, 64));
        m = fmaxf(m, __shfl_xor(m, 16, 64));
        m = fmaxf(m, __shfl_xor(m, 32, 64));
        float p1 = __expf(z1 - m), p2 = __expf(z2 - m);
        float se = p1 + p2;
        se += __shfl_xor(se, 8, 64);
        se += __shfl_xor(se, 16, 64);
        se += __shfl_xor(se, 32, 64);
        float inv = 1.0f / se;
        float wt1 = p1 * inv, wt2 = p2 * inv;
        float pix = p[i * 3 + 0], piy = p[i * 3 + 1], piz = p[i * 3 + 2];
        int nb16 = (lane < 16) ? idx[i * 16 + lane] : 0;
        float acc = 0.f;
        #pragma unroll
        for (int j = 0; j < 16; ++j) {
            int nb = __shfl(nb16, j, 64);
            float g0 = p[nb * 3 + 0] - pix;
            float g1 = p[nb * 3 + 1] - piy;
            float g2 = p[nb * 3 + 2] - piz;
            float e0 = relu_((b10 + w10 * g0 + w11 * g1 + w12 * g2) * sp0 + hp0);
            float e1 = relu_((b11 + w13 * g0 + w14 * g1 + w15 * g2) * sp1 + hp1);
            float e2 = relu_((b12 + w16 * g0 + w17 * g1 + w18 * g2) * sp2 + hp2);
            float pr = bc + wa * e0 + wb * e1 + wc * e2;
            float gv = ubf(xvh[(size_t)nb * 32 + (lane >> 1)], sel);
            float wgt = __shfl(j < 8 ? wt1 : wt2, ((j & 7) << 3) + qq, 64);
            acc = fmaf(gv + pr, wgt, acc);
        }
        out[(size_t)i * 64 + lane] = acc;
    }
}

extern "C" void kernel_launch(void* const* d_in, const int* in_sizes, int n_in,
                              void* d_out, int out_size, void* d_ws, size_t ws_size,
                              hipStream_t stream) {
    const float* p    = (const float*)d_in[0];
    const float* x    = (const float*)d_in[1];
    const int*   idx  = (const int*)d_in[2];
    const float* Wq   = (const float*)d_in[3];
    const float* bq   = (const float*)d_in[4];
    const float* Wk   = (const float*)d_in[5];
    const float* bk   = (const float*)d_in[6];
    const float* Wv   = (const float*)d_in[7];
    const float* bv   = (const float*)d_in[8];
    const float* Wp1  = (const float*)d_in[9];
    const float* bp1  = (const float*)d_in[10];
    const float* bnpg = (const float*)d_in[11];
    const float* bnpb = (const float*)d_in[12];
    const float* Wp2  = (const float*)d_in[13];
    const float* bp2  = (const float*)d_in[14];
    const float* bn0g = (const float*)d_in[15];
    const float* bn0b = (const float*)d_in[16];
    const float* Ww1  = (const float*)d_in[17];
    const float* bw1  = (const float*)d_in[18];
    const float* bn1g = (const float*)d_in[19];
    const float* bn1b = (const float*)d_in[20];
    const float* Ww2  = (const float*)d_in[21];
    const float* bw2  = (const float*)d_in[22];

    int n = in_sizes[1] / 64;     // 65536
    int M = n * 16;               // n * ns
    float invM = 1.0f / (float)M;

    // workspace layout
    unsigned* xqh = (unsigned*)d_ws;                   // n*32
    unsigned* xkh = xqh + (size_t)n * 32;
    unsigned* xvh = xkh + (size_t)n * 32;
    unsigned* uh  = xvh + (size_t)n * 32;              // M*4
    float* part1 = (float*)(uh + (size_t)M * 4);       // NB_STAT*6
    float* part2 = part1 + (size_t)NB_STAT * 6;        // NB_STAT*128
    float* part3 = part2 + (size_t)NB_STAT * 128;      // NB_STAT*16
    float* bnp   = part3 + (size_t)NB_STAT * 16;       // 6 (pad 8)
    float* bnw0  = bnp + 8;                            // 128
    float* bnw1  = bnw0 + 128;                         // 16

    k_proj2<<<n / 32, 256, 0, stream>>>(x, Wq, bq, Wk, bk, Wv, bv, xqh, xkh, xvh);
    k_stats_p<<<NB_STAT, 256, 0, stream>>>(p, idx, Wp1, bp1, part1, M);
    k_fin_p<<<1, 64, 0, stream>>>(part1, NB_STAT, invM, bnpg, bnpb, bnp);
    k_stats_w<<<NB_STAT, 256, 0, stream>>>(p, idx, xqh, xkh, Wp1, bp1, bnp, Wp2, bp2, part2, n, NB_STAT * 4);
    k_fin_w0<<<1, 128, 0, stream>>>(part2, NB_STAT, invM, bn0g, bn0b, bnw0);
    k_u2<<<NB_STAT, 256, 0, stream>>>(p, idx, xqh, xkh, Wp1, bp1, bnp, Wp2, bp2, bnw0, Ww1, bw1, uh, part3, M);
    k_fin_w1<<<1, 16, 0, stream>>>(part3, NB_STAT, invM, bn1g, bn1b, bnw1);
    k_out2<<<2048, 256, 0, stream>>>(p, idx, xvh, uh, Wp1, bp1, bnp, Wp2, bp2, bnw1, Ww2, bw2, (float*)d_out, n, 2048 * 4);
}